// Round 1
// baseline (3743.357 us; speedup 1.0000x reference)
//
#include <hip/hip_runtime.h>
#include <math.h>

#define NEG_SLOPE 0.2f
#define GAT_EPS 1e-16f

// ---------- float ordered-uint encoding for atomicMax on floats ----------
__device__ __forceinline__ unsigned enc_f(float f) {
    unsigned u = __float_as_uint(f);
    return (u & 0x80000000u) ? ~u : (u | 0x80000000u);
}
__device__ __forceinline__ float dec_f(unsigned e) {
    return __uint_as_float((e & 0x80000000u) ? (e & 0x7FFFFFFFu) : ~e);
}

__device__ __forceinline__ float leaky(float v) {
    return v > 0.f ? v : NEG_SLOPE * v;
}

// ---------- GEMM1: h1p[N,256] = x[N,128] @ W1[128,256] (f32 vector ALU) ----------
__global__ __launch_bounds__(256) void gemm1_kernel(
    const float* __restrict__ x, const float* __restrict__ W,
    float* __restrict__ h, int N)
{
    __shared__ float As[64][64];  // As[k][r]  (transposed chunk of x)
    __shared__ float Bs[64][64];  // Bs[k][c]
    const int row0 = blockIdx.x * 64;
    const int col0 = blockIdx.y * 64;
    const int tid = threadIdx.x;
    const int tx = tid & 15, ty = tid >> 4;
    float acc[4][4] = {};
    for (int kc = 0; kc < 128; kc += 64) {
        // load A chunk (transpose into LDS)
        {
            int r = tid & 63;        // 0..63
            int kq = tid >> 6;       // 0..3
            int row = row0 + r; if (row > N - 1) row = N - 1;
            const float4* xp = (const float4*)(x + (size_t)row * 128 + kc + kq * 16);
            #pragma unroll
            for (int j = 0; j < 4; ++j) {
                float4 v = xp[j];
                int kl = kq * 16 + j * 4;
                As[kl + 0][r] = v.x; As[kl + 1][r] = v.y;
                As[kl + 2][r] = v.z; As[kl + 3][r] = v.w;
            }
        }
        // load B chunk
        {
            int c4 = (tid & 15) * 4;
            int kl0 = tid >> 4;      // 0..15
            #pragma unroll
            for (int t = 0; t < 4; ++t) {
                int kl = kl0 + t * 16;
                float4 v = *(const float4*)&W[(size_t)(kc + kl) * 256 + col0 + c4];
                *(float4*)&Bs[kl][c4] = v;
            }
        }
        __syncthreads();
        #pragma unroll
        for (int k = 0; k < 64; ++k) {
            float4 a = *(const float4*)&As[k][ty * 4];
            float4 b = *(const float4*)&Bs[k][tx * 4];
            acc[0][0] += a.x * b.x; acc[0][1] += a.x * b.y; acc[0][2] += a.x * b.z; acc[0][3] += a.x * b.w;
            acc[1][0] += a.y * b.x; acc[1][1] += a.y * b.y; acc[1][2] += a.y * b.z; acc[1][3] += a.y * b.w;
            acc[2][0] += a.z * b.x; acc[2][1] += a.z * b.y; acc[2][2] += a.z * b.z; acc[2][3] += a.z * b.w;
            acc[3][0] += a.w * b.x; acc[3][1] += a.w * b.y; acc[3][2] += a.w * b.z; acc[3][3] += a.w * b.w;
        }
        __syncthreads();
    }
    #pragma unroll
    for (int i = 0; i < 4; ++i) {
        int row = row0 + ty * 4 + i;
        if (row < N) {
            float4 v = make_float4(acc[i][0], acc[i][1], acc[i][2], acc[i][3]);
            *(float4*)&h[(size_t)row * 256 + col0 + tx * 4] = v;
        }
    }
}

// ---------- per-node attention logits: as1/ad1 [N,8] ----------
__global__ void alpha1_kernel(const float* __restrict__ h1p,
    const float* __restrict__ a_src, const float* __restrict__ a_dst,
    float* __restrict__ as1, float* __restrict__ ad1, int N)
{
    int t = blockIdx.x * blockDim.x + threadIdx.x;
    if (t >= N * 8) return;
    int n = t >> 3, hh = t & 7;
    const float4* hp  = (const float4*)(h1p + (size_t)n * 256 + hh * 32);
    const float4* asp = (const float4*)(a_src + hh * 32);
    const float4* adp = (const float4*)(a_dst + hh * 32);
    float ss = 0.f, sd = 0.f;
    #pragma unroll
    for (int j = 0; j < 8; ++j) {
        float4 hv = hp[j], av = asp[j], dv = adp[j];
        ss += hv.x * av.x + hv.y * av.y + hv.z * av.z + hv.w * av.w;
        sd += hv.x * dv.x + hv.y * dv.y + hv.z * dv.z + hv.w * dv.w;
    }
    as1[t] = ss; ad1[t] = sd;
}

// ---------- edge pass 1: segment max (per dst, per head) ----------
__global__ void edge_max1(const int* __restrict__ ei, int E, int ET,
    const float* __restrict__ as1, const float* __restrict__ ad1,
    unsigned* __restrict__ m1)
{
    int i = blockIdx.x * blockDim.x + threadIdx.x;
    if (i >= ET) return;
    int src = (i < E) ? ei[i] : (i - E);
    int dst = (i < E) ? ei[E + i] : (i - E);
    const float4* sp = (const float4*)(as1 + (size_t)src * 8);
    const float4* dp = (const float4*)(ad1 + (size_t)dst * 8);
    float4 s0 = sp[0], s1v = sp[1], d0 = dp[0], d1v = dp[1];
    float e[8] = { s0.x + d0.x, s0.y + d0.y, s0.z + d0.z, s0.w + d0.w,
                   s1v.x + d1v.x, s1v.y + d1v.y, s1v.z + d1v.z, s1v.w + d1v.w };
    unsigned* mp = m1 + (size_t)dst * 8;
    #pragma unroll
    for (int hh = 0; hh < 8; ++hh) atomicMax(&mp[hh], enc_f(leaky(e[hh])));
}

// ---------- edge pass 2: segment sum of exp(e - m) ----------
__global__ void edge_sum1(const int* __restrict__ ei, int E, int ET,
    const float* __restrict__ as1, const float* __restrict__ ad1,
    const unsigned* __restrict__ m1, float* __restrict__ s1)
{
    int i = blockIdx.x * blockDim.x + threadIdx.x;
    if (i >= ET) return;
    int src = (i < E) ? ei[i] : (i - E);
    int dst = (i < E) ? ei[E + i] : (i - E);
    const float4* sp = (const float4*)(as1 + (size_t)src * 8);
    const float4* dp = (const float4*)(ad1 + (size_t)dst * 8);
    float4 s0 = sp[0], s1v = sp[1], d0 = dp[0], d1v = dp[1];
    float e[8] = { s0.x + d0.x, s0.y + d0.y, s0.z + d0.z, s0.w + d0.w,
                   s1v.x + d1v.x, s1v.y + d1v.y, s1v.z + d1v.z, s1v.w + d1v.w };
    const unsigned* mp = m1 + (size_t)dst * 8;
    float* sp1 = s1 + (size_t)dst * 8;
    #pragma unroll
    for (int hh = 0; hh < 8; ++hh) {
        float ex = __expf(leaky(e[hh]) - dec_f(mp[hh]));
        unsafeAtomicAdd(&sp1[hh], ex);
    }
}

// ---------- edge pass 3: weighted scatter-aggregate (wave per edge) ----------
__global__ __launch_bounds__(256) void edge_aggr1(const int* __restrict__ ei, int E, int ET,
    const float* __restrict__ as1, const float* __restrict__ ad1,
    const unsigned* __restrict__ m1, const float* __restrict__ s1,
    const float* __restrict__ h1p, float* __restrict__ out1)
{
    int wave = blockIdx.x * 4 + (threadIdx.x >> 6);
    int lane = threadIdx.x & 63;
    if (wave >= ET) return;
    int src = (wave < E) ? ei[wave] : (wave - E);
    int dst = (wave < E) ? ei[E + wave] : (wave - E);
    int hh = lane >> 3;                       // head = (lane*4)/32
    float e = leaky(as1[(size_t)src * 8 + hh] + ad1[(size_t)dst * 8 + hh]);
    float alpha = __expf(e - dec_f(m1[(size_t)dst * 8 + hh])) /
                  (s1[(size_t)dst * 8 + hh] + GAT_EPS);
    float4 hv = *(const float4*)&h1p[(size_t)src * 256 + lane * 4];
    float* op = out1 + (size_t)dst * 256 + lane * 4;
    unsafeAtomicAdd(op + 0, hv.x * alpha);
    unsafeAtomicAdd(op + 1, hv.y * alpha);
    unsafeAtomicAdd(op + 2, hv.z * alpha);
    unsafeAtomicAdd(op + 3, hv.w * alpha);
}

// ---------- bias + ELU (in place on out1) ----------
__global__ void bias_elu(float* __restrict__ out1, const float* __restrict__ bias, int N)
{
    int idx = blockIdx.x * blockDim.x + threadIdx.x;  // one float4 each
    if (idx >= N * 64) return;
    int j4 = (idx & 63) * 4;
    float4 v = *(float4*)&out1[(size_t)idx * 4];
    float4 b = *(const float4*)&bias[j4];
    v.x += b.x; v.y += b.y; v.z += b.z; v.w += b.w;
    v.x = v.x > 0.f ? v.x : __expf(v.x) - 1.f;
    v.y = v.y > 0.f ? v.y : __expf(v.y) - 1.f;
    v.z = v.z > 0.f ? v.z : __expf(v.z) - 1.f;
    v.w = v.w > 0.f ? v.w : __expf(v.w) - 1.f;
    *(float4*)&out1[(size_t)idx * 4] = v;
}

// ---------- GEMM2: h2[N] = h1f[N,256] @ W2[256,1]  (wave per node) ----------
__global__ __launch_bounds__(256) void gemm2_kernel(const float* __restrict__ h1f,
    const float* __restrict__ W2, float* __restrict__ h2, int N)
{
    int n = blockIdx.x * 4 + (threadIdx.x >> 6);
    int lane = threadIdx.x & 63;
    if (n >= N) return;
    float4 hv = *(const float4*)&h1f[(size_t)n * 256 + lane * 4];
    float4 wv = *(const float4*)&W2[lane * 4];
    float v = hv.x * wv.x + hv.y * wv.y + hv.z * wv.z + hv.w * wv.w;
    #pragma unroll
    for (int off = 32; off; off >>= 1) v += __shfl_down(v, off);
    if (lane == 0) h2[n] = v;
}

// ---------- layer-2 edge passes (scalar, thread per edge) ----------
__global__ void edge_max2(const int* __restrict__ ei, int E, int ET,
    const float* __restrict__ h2, const float* __restrict__ a_s2,
    const float* __restrict__ a_d2, unsigned* __restrict__ m2)
{
    int i = blockIdx.x * blockDim.x + threadIdx.x;
    if (i >= ET) return;
    int src = (i < E) ? ei[i] : (i - E);
    int dst = (i < E) ? ei[E + i] : (i - E);
    float e = leaky(h2[src] * a_s2[0] + h2[dst] * a_d2[0]);
    atomicMax(&m2[dst], enc_f(e));
}

__global__ void edge_sum2(const int* __restrict__ ei, int E, int ET,
    const float* __restrict__ h2, const float* __restrict__ a_s2,
    const float* __restrict__ a_d2, const unsigned* __restrict__ m2,
    float* __restrict__ s2)
{
    int i = blockIdx.x * blockDim.x + threadIdx.x;
    if (i >= ET) return;
    int src = (i < E) ? ei[i] : (i - E);
    int dst = (i < E) ? ei[E + i] : (i - E);
    float e = leaky(h2[src] * a_s2[0] + h2[dst] * a_d2[0]);
    unsafeAtomicAdd(&s2[dst], __expf(e - dec_f(m2[dst])));
}

__global__ void edge_aggr2(const int* __restrict__ ei, int E, int ET,
    const float* __restrict__ h2, const float* __restrict__ a_s2,
    const float* __restrict__ a_d2, const unsigned* __restrict__ m2,
    const float* __restrict__ s2, float* __restrict__ out2)
{
    int i = blockIdx.x * blockDim.x + threadIdx.x;
    if (i >= ET) return;
    int src = (i < E) ? ei[i] : (i - E);
    int dst = (i < E) ? ei[E + i] : (i - E);
    float e = leaky(h2[src] * a_s2[0] + h2[dst] * a_d2[0]);
    float alpha = __expf(e - dec_f(m2[dst])) / (s2[dst] + GAT_EPS);
    unsafeAtomicAdd(&out2[dst], h2[src] * alpha);
}

__global__ void final_kernel(const float* __restrict__ out2,
    const float* __restrict__ bias2, float* __restrict__ out, int N)
{
    int n = blockIdx.x * blockDim.x + threadIdx.x;
    if (n >= N) return;
    float z = out2[n] + bias2[0];
    out[n] = 1.f / (1.f + __expf(-z));
}

extern "C" void kernel_launch(void* const* d_in, const int* in_sizes, int n_in,
                              void* d_out, int out_size, void* d_ws, size_t ws_size,
                              hipStream_t stream)
{
    const float* x      = (const float*)d_in[0];
    const int*   ei     = (const int*)  d_in[1];
    const float* W1     = (const float*)d_in[2];
    const float* a_src1 = (const float*)d_in[3];
    const float* a_dst1 = (const float*)d_in[4];
    const float* bias1  = (const float*)d_in[5];
    const float* W2     = (const float*)d_in[6];
    const float* a_s2   = (const float*)d_in[7];
    const float* a_d2   = (const float*)d_in[8];
    const float* bias2  = (const float*)d_in[9];
    float* out = (float*)d_out;

    const int N  = in_sizes[0] / 128;
    const int E  = in_sizes[1] / 2;
    const int ET = E + N;

    float* ws = (float*)d_ws;
    size_t off = 0;
    float* h1p = ws + off;            off += (size_t)N * 256;
    float* as1 = ws + off;            off += (size_t)N * 8;
    float* ad1 = ws + off;            off += (size_t)N * 8;
    float* h2  = ws + off;            off += (size_t)N;
    float* zstart = ws + off;         // ---- zero-initialized region below ----
    float* out1 = ws + off;           off += (size_t)N * 256;
    unsigned* m1 = (unsigned*)(ws + off); off += (size_t)N * 8;
    float* s1  = ws + off;            off += (size_t)N * 8;
    unsigned* m2 = (unsigned*)(ws + off); off += (size_t)N;
    float* s2  = ws + off;            off += (size_t)N;
    float* out2 = ws + off;           off += (size_t)N;

    // zero: out1(256N) + m1(8N) + s1(8N) + m2(N) + s2(N) + out2(N) = 275N floats
    hipMemsetAsync(zstart, 0, (size_t)N * 275 * sizeof(float), stream);

    dim3 g1((N + 63) / 64, 4);
    gemm1_kernel<<<g1, 256, 0, stream>>>(x, W1, h1p, N);
    alpha1_kernel<<<(N * 8 + 255) / 256, 256, 0, stream>>>(h1p, a_src1, a_dst1, as1, ad1, N);

    int eb = (ET + 255) / 256;
    edge_max1<<<eb, 256, 0, stream>>>(ei, E, ET, as1, ad1, m1);
    edge_sum1<<<eb, 256, 0, stream>>>(ei, E, ET, as1, ad1, m1, s1);
    edge_aggr1<<<(ET + 3) / 4, 256, 0, stream>>>(ei, E, ET, as1, ad1, m1, s1, h1p, out1);
    bias_elu<<<(N * 64 + 255) / 256, 256, 0, stream>>>(out1, bias1, N);

    gemm2_kernel<<<(N + 3) / 4, 256, 0, stream>>>(out1, W2, h2, N);
    edge_max2<<<eb, 256, 0, stream>>>(ei, E, ET, h2, a_s2, a_d2, m2);
    edge_sum2<<<eb, 256, 0, stream>>>(ei, E, ET, h2, a_s2, a_d2, m2, s2);
    edge_aggr2<<<eb, 256, 0, stream>>>(ei, E, ET, h2, a_s2, a_d2, m2, s2, out2);
    final_kernel<<<(N + 255) / 256, 256, 0, stream>>>(out2, bias2, out, N);
}

// Round 2
// 466.988 us; speedup vs baseline: 8.0160x; 8.0160x over previous
//
#include <hip/hip_runtime.h>
#include <math.h>

#define NEG_SLOPE 0.2f
#define GAT_EPS 1e-16f
#define NEG_BIG -3.0e38f

__device__ __forceinline__ float leaky(float v) {
    return v > 0.f ? v : NEG_SLOPE * v;
}

// ---------- GEMM1: h1p[N,256] = x[N,128] @ W1[128,256] (f32 vector ALU) ----------
__global__ __launch_bounds__(256) void gemm1_kernel(
    const float* __restrict__ x, const float* __restrict__ W,
    float* __restrict__ h, int N)
{
    __shared__ float As[64][64];  // As[k][r]  (transposed chunk of x)
    __shared__ float Bs[64][64];  // Bs[k][c]
    const int row0 = blockIdx.x * 64;
    const int col0 = blockIdx.y * 64;
    const int tid = threadIdx.x;
    const int tx = tid & 15, ty = tid >> 4;
    float acc[4][4] = {};
    for (int kc = 0; kc < 128; kc += 64) {
        {
            int r = tid & 63;
            int kq = tid >> 6;
            int row = row0 + r; if (row > N - 1) row = N - 1;
            const float4* xp = (const float4*)(x + (size_t)row * 128 + kc + kq * 16);
            #pragma unroll
            for (int j = 0; j < 4; ++j) {
                float4 v = xp[j];
                int kl = kq * 16 + j * 4;
                As[kl + 0][r] = v.x; As[kl + 1][r] = v.y;
                As[kl + 2][r] = v.z; As[kl + 3][r] = v.w;
            }
        }
        {
            int c4 = (tid & 15) * 4;
            int kl0 = tid >> 4;
            #pragma unroll
            for (int t = 0; t < 4; ++t) {
                int kl = kl0 + t * 16;
                float4 v = *(const float4*)&W[(size_t)(kc + kl) * 256 + col0 + c4];
                *(float4*)&Bs[kl][c4] = v;
            }
        }
        __syncthreads();
        #pragma unroll
        for (int k = 0; k < 64; ++k) {
            float4 a = *(const float4*)&As[k][ty * 4];
            float4 b = *(const float4*)&Bs[k][tx * 4];
            acc[0][0] += a.x * b.x; acc[0][1] += a.x * b.y; acc[0][2] += a.x * b.z; acc[0][3] += a.x * b.w;
            acc[1][0] += a.y * b.x; acc[1][1] += a.y * b.y; acc[1][2] += a.y * b.z; acc[1][3] += a.y * b.w;
            acc[2][0] += a.z * b.x; acc[2][1] += a.z * b.y; acc[2][2] += a.z * b.z; acc[2][3] += a.z * b.w;
            acc[3][0] += a.w * b.x; acc[3][1] += a.w * b.y; acc[3][2] += a.w * b.z; acc[3][3] += a.w * b.w;
        }
        __syncthreads();
    }
    #pragma unroll
    for (int i = 0; i < 4; ++i) {
        int row = row0 + ty * 4 + i;
        if (row < N) {
            float4 v = make_float4(acc[i][0], acc[i][1], acc[i][2], acc[i][3]);
            *(float4*)&h[(size_t)row * 256 + col0 + tx * 4] = v;
        }
    }
}

// ---------- per-node attention logits: as1/ad1 [N,8] ----------
__global__ void alpha1_kernel(const float* __restrict__ h1p,
    const float* __restrict__ a_src, const float* __restrict__ a_dst,
    float* __restrict__ as1, float* __restrict__ ad1, int N)
{
    int t = blockIdx.x * blockDim.x + threadIdx.x;
    if (t >= N * 8) return;
    int n = t >> 3, hh = t & 7;
    const float4* hp  = (const float4*)(h1p + (size_t)n * 256 + hh * 32);
    const float4* asp = (const float4*)(a_src + hh * 32);
    const float4* adp = (const float4*)(a_dst + hh * 32);
    float ss = 0.f, sd = 0.f;
    #pragma unroll
    for (int j = 0; j < 8; ++j) {
        float4 hv = hp[j], av = asp[j], dv = adp[j];
        ss += hv.x * av.x + hv.y * av.y + hv.z * av.z + hv.w * av.w;
        sd += hv.x * dv.x + hv.y * dv.y + hv.z * dv.z + hv.w * dv.w;
    }
    as1[t] = ss; ad1[t] = sd;
}

// ---------- CSR build ----------
__global__ void init_deg(int* __restrict__ deg, int N) {
    int n = blockIdx.x * blockDim.x + threadIdx.x;
    if (n < N) deg[n] = 1;   // self-loop
}

__global__ void count_deg(const int* __restrict__ ei, int E, int* __restrict__ deg) {
    int i = blockIdx.x * blockDim.x + threadIdx.x;
    if (i < E) atomicAdd(&deg[ei[E + i]], 1);
}

__global__ __launch_bounds__(1024) void scan_kernel(const int* __restrict__ deg,
    int* __restrict__ row_ptr, int* __restrict__ cursor, int N)
{
    __shared__ int buf[1024];
    __shared__ int s_carry;
    int t = threadIdx.x;
    if (t == 0) { s_carry = 0; row_ptr[0] = 0; }
    __syncthreads();
    for (int base = 0; base < N; base += 1024) {
        int c = s_carry;
        int v = (base + t < N) ? deg[base + t] : 0;
        buf[t] = v;
        __syncthreads();
        for (int off = 1; off < 1024; off <<= 1) {
            int add = (t >= off) ? buf[t - off] : 0;
            __syncthreads();
            buf[t] += add;
            __syncthreads();
        }
        int incl = buf[t];
        int tot = buf[1023];
        if (base + t < N) {
            row_ptr[base + t + 1] = c + incl;
            cursor[base + t] = c + incl - v;
        }
        __syncthreads();
        if (t == 0) s_carry = c + tot;
        __syncthreads();
    }
}

// scatter edges into CSR order + compute per-edge post-leaky logits (8 heads)
__global__ void scatter_logits(const int* __restrict__ ei, int E, int ET,
    const float* __restrict__ as1, const float* __restrict__ ad1,
    int* __restrict__ cursor, int* __restrict__ csr_src, float* __restrict__ elogit)
{
    int i = blockIdx.x * blockDim.x + threadIdx.x;
    if (i >= ET) return;
    int src = (i < E) ? ei[i] : (i - E);
    int dst = (i < E) ? ei[E + i] : (i - E);
    int pos = atomicAdd(&cursor[dst], 1);
    csr_src[pos] = src;
    const float4* sp = (const float4*)(as1 + (size_t)src * 8);
    const float4* dp = (const float4*)(ad1 + (size_t)dst * 8);
    float4 s0 = sp[0], s1 = sp[1], d0 = dp[0], d1 = dp[1];
    float4 e0 = make_float4(leaky(s0.x + d0.x), leaky(s0.y + d0.y),
                            leaky(s0.z + d0.z), leaky(s0.w + d0.w));
    float4 e1 = make_float4(leaky(s1.x + d1.x), leaky(s1.y + d1.y),
                            leaky(s1.z + d1.z), leaky(s1.w + d1.w));
    *(float4*)&elogit[(size_t)pos * 8]     = e0;
    *(float4*)&elogit[(size_t)pos * 8 + 4] = e1;
}

// ---------- fused layer-1 aggregation: softmax + weighted gather + bias + ELU + GEMM2
// one wave per destination node; 64 lanes own 4 output floats each.
// lane layout for logit chunks: lane -> (edge j = lane>>3, head = lane&7)
__global__ __launch_bounds__(256) void aggr1_fused(
    const int* __restrict__ row_ptr, const int* __restrict__ csr_src,
    const float* __restrict__ elogit, const float* __restrict__ h1p,
    const float* __restrict__ bias1, const float* __restrict__ W2,
    float* __restrict__ h2, int N)
{
    int n = blockIdx.x * 4 + (threadIdx.x >> 6);
    int lane = threadIdx.x & 63;
    if (n >= N) return;
    int rs = row_ptr[n];
    int deg = row_ptr[n + 1] - rs;

    // pass 1: per-lane online softmax (edges lane>>3 + 8t, head lane&7)
    float m = NEG_BIG, s = 0.f;
    for (int j0 = 0; j0 < deg; j0 += 8) {
        int idx = j0 + (lane >> 3);
        if (idx < deg) {
            float l = elogit[(size_t)(rs + j0) * 8 + lane];
            if (l > m) { s = s * __expf(m - l) + 1.f; m = l; }
            else       { s += __expf(l - m); }
        }
    }
    // combine across the 8 lanes sharing a head (xor 8,16,32)
    #pragma unroll
    for (int mask = 8; mask < 64; mask <<= 1) {
        float mo = __shfl_xor(m, mask);
        float so = __shfl_xor(s, mask);
        float M = fmaxf(m, mo);
        s = s * __expf(m - M) + so * __expf(mo - M);
        m = M;
    }
    float inv = 1.f / (s + GAT_EPS);

    // pass 2: weighted aggregation
    float4 acc = make_float4(0.f, 0.f, 0.f, 0.f);
    int hh = lane >> 3;   // head owning this lane's float4 of the 256-dim output
    for (int j0 = 0; j0 < deg; j0 += 8) {
        int idx = j0 + (lane >> 3);
        float p = 0.f;
        if (idx < deg) {
            float l = elogit[(size_t)(rs + j0) * 8 + lane];
            p = __expf(l - m) * inv;
        }
        int sv = 0;
        if (lane < 8 && j0 + lane < deg) sv = csr_src[rs + j0 + lane];
        int cnt = min(8, deg - j0);
        for (int j = 0; j < cnt; ++j) {
            int srcj = __shfl(sv, j);
            float a  = __shfl(p, (j << 3) | hh);
            float4 hv = *(const float4*)&h1p[(size_t)srcj * 256 + lane * 4];
            acc.x += a * hv.x; acc.y += a * hv.y;
            acc.z += a * hv.z; acc.w += a * hv.w;
        }
    }

    // fused epilogue: +bias1, ELU, dot with W2, wave-reduce -> h2[n]
    float4 b = *(const float4*)&bias1[lane * 4];
    acc.x += b.x; acc.y += b.y; acc.z += b.z; acc.w += b.w;
    acc.x = acc.x > 0.f ? acc.x : __expf(acc.x) - 1.f;
    acc.y = acc.y > 0.f ? acc.y : __expf(acc.y) - 1.f;
    acc.z = acc.z > 0.f ? acc.z : __expf(acc.z) - 1.f;
    acc.w = acc.w > 0.f ? acc.w : __expf(acc.w) - 1.f;
    float4 w = *(const float4*)&W2[lane * 4];
    float part = acc.x * w.x + acc.y * w.y + acc.z * w.z + acc.w * w.w;
    #pragma unroll
    for (int mask = 1; mask < 64; mask <<= 1) part += __shfl_xor(part, mask);
    if (lane == 0) h2[n] = part;
}

// ---------- fused layer-2: softmax + aggregate + bias + sigmoid (wave per node) ----------
__global__ __launch_bounds__(256) void layer2_fused(
    const int* __restrict__ row_ptr, const int* __restrict__ csr_src,
    const float* __restrict__ h2, const float* __restrict__ a_s2,
    const float* __restrict__ a_d2, const float* __restrict__ bias2,
    float* __restrict__ out, int N)
{
    int n = blockIdx.x * 4 + (threadIdx.x >> 6);
    int lane = threadIdx.x & 63;
    if (n >= N) return;
    int rs = row_ptr[n];
    int deg = row_ptr[n + 1] - rs;
    float asc = a_s2[0], adc = a_d2[0];
    float hdc = h2[n] * adc;

    float m = NEG_BIG, s = 0.f;
    for (int k = lane; k < deg; k += 64) {
        float hs = h2[csr_src[rs + k]];
        float l = leaky(hs * asc + hdc);
        if (l > m) { s = s * __expf(m - l) + 1.f; m = l; }
        else       { s += __expf(l - m); }
    }
    #pragma unroll
    for (int mask = 1; mask < 64; mask <<= 1) {
        float mo = __shfl_xor(m, mask);
        float so = __shfl_xor(s, mask);
        float M = fmaxf(m, mo);
        s = s * __expf(m - M) + so * __expf(mo - M);
        m = M;
    }
    float inv = 1.f / (s + GAT_EPS);

    float acc = 0.f;
    for (int k = lane; k < deg; k += 64) {
        float hs = h2[csr_src[rs + k]];
        float l = leaky(hs * asc + hdc);
        acc += __expf(l - m) * inv * hs;
    }
    #pragma unroll
    for (int mask = 1; mask < 64; mask <<= 1) acc += __shfl_xor(acc, mask);
    if (lane == 0) {
        float z = acc + bias2[0];
        out[n] = 1.f / (1.f + __expf(-z));
    }
}

extern "C" void kernel_launch(void* const* d_in, const int* in_sizes, int n_in,
                              void* d_out, int out_size, void* d_ws, size_t ws_size,
                              hipStream_t stream)
{
    const float* x      = (const float*)d_in[0];
    const int*   ei     = (const int*)  d_in[1];
    const float* W1     = (const float*)d_in[2];
    const float* a_src1 = (const float*)d_in[3];
    const float* a_dst1 = (const float*)d_in[4];
    const float* bias1  = (const float*)d_in[5];
    const float* W2     = (const float*)d_in[6];
    const float* a_s2   = (const float*)d_in[7];
    const float* a_d2   = (const float*)d_in[8];
    const float* bias2  = (const float*)d_in[9];
    float* out = (float*)d_out;

    const int N  = in_sizes[0] / 128;
    const int E  = in_sizes[1] / 2;
    const int ET = E + N;

    float* ws = (float*)d_ws;
    size_t off = 0;
    float* h1p = ws + off;                 off += (size_t)N * 256;
    float* as1 = ws + off;                 off += (size_t)N * 8;
    float* ad1 = ws + off;                 off += (size_t)N * 8;
    float* h2  = ws + off;                 off += (size_t)N;
    int* deg     = (int*)(ws + off);       off += (size_t)N;
    int* cursor  = (int*)(ws + off);       off += (size_t)N;
    int* row_ptr = (int*)(ws + off);       off += (size_t)N + 4;
    int* csr_src = (int*)(ws + off);       off += (size_t)ET + 16;
    float* elogit = ws + off;              off += (size_t)ET * 8 + 64;

    // --- CSR build (independent of gemm1) ---
    init_deg<<<(N + 255) / 256, 256, 0, stream>>>(deg, N);
    count_deg<<<(E + 255) / 256, 256, 0, stream>>>(ei, E, deg);
    scan_kernel<<<1, 1024, 0, stream>>>(deg, row_ptr, cursor, N);

    // --- layer 1 projection + logits ---
    dim3 g1((N + 63) / 64, 4);
    gemm1_kernel<<<g1, 256, 0, stream>>>(x, W1, h1p, N);
    alpha1_kernel<<<(N * 8 + 255) / 256, 256, 0, stream>>>(h1p, a_src1, a_dst1, as1, ad1, N);

    scatter_logits<<<(ET + 255) / 256, 256, 0, stream>>>(ei, E, ET, as1, ad1,
                                                         cursor, csr_src, elogit);

    // --- fused aggregation layers ---
    aggr1_fused<<<(N + 3) / 4, 256, 0, stream>>>(row_ptr, csr_src, elogit, h1p,
                                                 bias1, W2, h2, N);
    layer2_fused<<<(N + 3) / 4, 256, 0, stream>>>(row_ptr, csr_src, h2,
                                                  a_s2, a_d2, bias2, out, N);
}

// Round 3
// 318.900 us; speedup vs baseline: 11.7383x; 1.4644x over previous
//
#include <hip/hip_runtime.h>
#include <math.h>

#define NEG_SLOPE 0.2f
#define GAT_EPS 1e-16f
#define NEG_BIG -3.0e38f

typedef __attribute__((ext_vector_type(8))) short short8;
typedef __attribute__((ext_vector_type(4))) float floatx4;

__device__ __forceinline__ float leaky(float v) {
    return v > 0.f ? v : NEG_SLOPE * v;
}
// fp32 -> bf16 round-to-nearest-even
__device__ __forceinline__ unsigned short f2bf(float f) {
    unsigned u = __float_as_uint(f);
    unsigned r = u + 0x7FFFu + ((u >> 16) & 1u);
    return (unsigned short)(r >> 16);
}
__device__ __forceinline__ float bf2f(unsigned short h) {
    return __uint_as_float(((unsigned)h) << 16);
}

// ---------- prep: x -> bf16, W1 -> bf16 transposed [256][128], deg init ----------
__global__ void prep_kernel(const float* __restrict__ x, const float* __restrict__ W1,
    unsigned short* __restrict__ xb, unsigned short* __restrict__ w1t,
    int* __restrict__ deg, int N)
{
    int idx = blockIdx.x * blockDim.x + threadIdx.x;
    int nx4 = N * 32;                       // N*128/4 float4 groups
    if (idx < nx4) {
        float4 v = *(const float4*)&x[(size_t)idx * 4];
        ushort4 o;
        o.x = f2bf(v.x); o.y = f2bf(v.y); o.z = f2bf(v.z); o.w = f2bf(v.w);
        *(ushort4*)&xb[(size_t)idx * 4] = o;
    }
    if (idx < 128 * 256) {                  // w1t[n][k] = W1[k][n]
        int n = idx >> 7, k = idx & 127;
        w1t[idx] = f2bf(W1[(size_t)k * 256 + n]);
    }
    if (idx < N) deg[idx] = 1;              // self-loop
}

// ---------- GEMM1 via bf16 MFMA: h1b[N,256](bf16) = xb[N,128] @ W1 ----------
// 64 rows/block, full 256 cols, K=128 in chunks of 32. 256 threads = 4 waves.
__global__ __launch_bounds__(256) void gemm1_mfma(
    const unsigned short* __restrict__ xb, const unsigned short* __restrict__ w1t,
    unsigned short* __restrict__ h1b, int N)
{
    __shared__ __align__(16) unsigned short Asl[64][40];   // [row][k] pad->40
    __shared__ __align__(16) unsigned short Bsl[256][40];  // [n][k]   pad->40
    const int row0 = blockIdx.x * 64;
    const int tid = threadIdx.x;
    const int wave = tid >> 6, lane = tid & 63;
    const int l15 = lane & 15, quad = lane >> 4;

    floatx4 acc[16];
    #pragma unroll
    for (int i = 0; i < 16; ++i) acc[i] = (floatx4){0.f, 0.f, 0.f, 0.f};

    for (int kc = 0; kc < 128; kc += 32) {
        // stage A: 64 rows x 32 k (one 16B chunk per thread)
        {
            int r = tid >> 2, q = tid & 3;
            int row = row0 + r; if (row > N - 1) row = N - 1;
            uint4 v = *(const uint4*)&xb[(size_t)row * 128 + kc + q * 8];
            *(uint4*)&Asl[r][q * 8] = v;
        }
        // stage B: 256 n x 32 k (4 x 16B chunks per thread)
        {
            int n = tid;
            #pragma unroll
            for (int q = 0; q < 4; ++q) {
                uint4 v = *(const uint4*)&w1t[(size_t)n * 128 + kc + q * 8];
                *(uint4*)&Bsl[n][q * 8] = v;
            }
        }
        __syncthreads();
        short8 a = *(const short8*)&Asl[wave * 16 + l15][quad * 8];
        #pragma unroll
        for (int nt = 0; nt < 16; ++nt) {
            short8 b = *(const short8*)&Bsl[nt * 16 + l15][quad * 8];
            acc[nt] = __builtin_amdgcn_mfma_f32_16x16x32_bf16(a, b, acc[nt], 0, 0, 0);
        }
        __syncthreads();
    }
    // epilogue: D row = quad*4+reg, col = nt*16+l15
    #pragma unroll
    for (int reg = 0; reg < 4; ++reg) {
        int row = row0 + wave * 16 + quad * 4 + reg;
        if (row < N) {
            #pragma unroll
            for (int nt = 0; nt < 16; ++nt)
                h1b[(size_t)row * 256 + nt * 16 + l15] = f2bf(acc[nt][reg]);
        }
    }
}

// ---------- per-node attention logits from bf16 h ----------
__global__ void alpha1_kernel(const unsigned short* __restrict__ h1b,
    const float* __restrict__ a_src, const float* __restrict__ a_dst,
    float* __restrict__ as1, float* __restrict__ ad1, int N)
{
    int t = blockIdx.x * blockDim.x + threadIdx.x;
    if (t >= N * 8) return;
    int n = t >> 3, hh = t & 7;
    const unsigned short* hp = h1b + (size_t)n * 256 + hh * 32;
    const float4* asp = (const float4*)(a_src + hh * 32);
    const float4* adp = (const float4*)(a_dst + hh * 32);
    float ss = 0.f, sd = 0.f;
    #pragma unroll
    for (int j = 0; j < 8; ++j) {
        ushort4 hv4 = *(const ushort4*)&hp[j * 4];
        float4 av = asp[j], dv = adp[j];
        float h0 = bf2f(hv4.x), h1 = bf2f(hv4.y), h2 = bf2f(hv4.z), h3 = bf2f(hv4.w);
        ss += h0 * av.x + h1 * av.y + h2 * av.z + h3 * av.w;
        sd += h0 * dv.x + h1 * dv.y + h2 * dv.z + h3 * dv.w;
    }
    as1[t] = ss; ad1[t] = sd;
}

// ---------- CSR build ----------
__global__ void count_deg(const int* __restrict__ ei, int E, int* __restrict__ deg) {
    int i = blockIdx.x * blockDim.x + threadIdx.x;
    if (i < E) atomicAdd(&deg[ei[E + i]], 1);
}

// 3-phase scan (N <= 65536): A) per-block(1024) inclusive scan, B) scan of 64 block sums, C) combine
__global__ __launch_bounds__(256) void scan_a(const int* __restrict__ deg,
    int* __restrict__ incl, int* __restrict__ bsum, int N)
{
    __shared__ int wsum[4];
    int t = threadIdx.x, b = blockIdx.x;
    int lane = t & 63, wv = t >> 6;
    int i0 = b * 1024 + t * 4;
    int v0 = (i0 + 0 < N) ? deg[i0 + 0] : 0;
    int v1 = (i0 + 1 < N) ? deg[i0 + 1] : 0;
    int v2 = (i0 + 2 < N) ? deg[i0 + 2] : 0;
    int v3 = (i0 + 3 < N) ? deg[i0 + 3] : 0;
    int tsum = v0 + v1 + v2 + v3;
    int x = tsum;
    #pragma unroll
    for (int off = 1; off < 64; off <<= 1) {
        int y = __shfl_up(x, off);
        if (lane >= off) x += y;
    }
    if (lane == 63) wsum[wv] = x;
    __syncthreads();
    int woff = 0;
    #pragma unroll
    for (int w = 0; w < 4; ++w) if (w < wv) woff += wsum[w];
    int run = woff + x - tsum;   // exclusive prefix of this thread's group
    run += v0; if (i0 + 0 < N) incl[i0 + 0] = run;
    run += v1; if (i0 + 1 < N) incl[i0 + 1] = run;
    run += v2; if (i0 + 2 < N) incl[i0 + 2] = run;
    run += v3; if (i0 + 3 < N) incl[i0 + 3] = run;
    if (t == 0) { /* nothing */ }
    __syncthreads();
    if (t == 255) bsum[b] = woff + x;   // block total (last thread inclusive)
}

__global__ void scan_b(int* __restrict__ bsum, int* __restrict__ boff, int nb) {
    int t = threadIdx.x;             // single block of 64
    int v = (t < nb) ? bsum[t] : 0;
    int x = v;
    #pragma unroll
    for (int off = 1; off < 64; off <<= 1) {
        int y = __shfl_up(x, off);
        if (t >= off) x += y;
    }
    if (t < nb) boff[t] = x - v;     // exclusive
}

__global__ __launch_bounds__(256) void scan_c(const int* __restrict__ incl,
    const int* __restrict__ boff, const int* __restrict__ deg,
    int* __restrict__ row_ptr, int* __restrict__ cursor, int N)
{
    int t = threadIdx.x, b = blockIdx.x;
    int base = boff[b];
    int i0 = b * 1024 + t * 4;
    #pragma unroll
    for (int j = 0; j < 4; ++j) {
        int i = i0 + j;
        if (i < N) {
            int ip = base + incl[i];
            row_ptr[i + 1] = ip;
            cursor[i] = ip - deg[i];
        }
    }
    if (b == 0 && t == 0) row_ptr[0] = 0;
}

// scatter edges into CSR order + per-edge post-leaky logits (8 heads)
__global__ void scatter_logits(const int* __restrict__ ei, int E, int ET,
    const float* __restrict__ as1, const float* __restrict__ ad1,
    int* __restrict__ cursor, int* __restrict__ csr_src, float* __restrict__ elogit)
{
    int i = blockIdx.x * blockDim.x + threadIdx.x;
    if (i >= ET) return;
    int src = (i < E) ? ei[i] : (i - E);
    int dst = (i < E) ? ei[E + i] : (i - E);
    int pos = atomicAdd(&cursor[dst], 1);
    csr_src[pos] = src;
    const float4* sp = (const float4*)(as1 + (size_t)src * 8);
    const float4* dp = (const float4*)(ad1 + (size_t)dst * 8);
    float4 s0 = sp[0], s1 = sp[1], d0 = dp[0], d1 = dp[1];
    float4 e0 = make_float4(leaky(s0.x + d0.x), leaky(s0.y + d0.y),
                            leaky(s0.z + d0.z), leaky(s0.w + d0.w));
    float4 e1 = make_float4(leaky(s1.x + d1.x), leaky(s1.y + d1.y),
                            leaky(s1.z + d1.z), leaky(s1.w + d1.w));
    *(float4*)&elogit[(size_t)pos * 8]     = e0;
    *(float4*)&elogit[(size_t)pos * 8 + 4] = e1;
}

// ---------- fused layer-1 aggregation + bias + ELU + GEMM2 (wave per node) ----------
__global__ __launch_bounds__(256) void aggr1_fused(
    const int* __restrict__ row_ptr, const int* __restrict__ csr_src,
    const float* __restrict__ elogit, const unsigned short* __restrict__ h1b,
    const float* __restrict__ bias1, const float* __restrict__ W2,
    float* __restrict__ h2, int N)
{
    int n = blockIdx.x * 4 + (threadIdx.x >> 6);
    int lane = threadIdx.x & 63;
    if (n >= N) return;
    int rs = row_ptr[n];
    int deg = row_ptr[n + 1] - rs;

    // pass 1: online softmax; lane -> (edge j0 + (lane>>3), head lane&7)
    float m = NEG_BIG, s = 0.f;
    for (int j0 = 0; j0 < deg; j0 += 8) {
        int idx = j0 + (lane >> 3);
        if (idx < deg) {
            float l = elogit[(size_t)(rs + j0) * 8 + lane];
            if (l > m) { s = s * __expf(m - l) + 1.f; m = l; }
            else       { s += __expf(l - m); }
        }
    }
    #pragma unroll
    for (int mask = 8; mask < 64; mask <<= 1) {
        float mo = __shfl_xor(m, mask);
        float so = __shfl_xor(s, mask);
        float M = fmaxf(m, mo);
        s = s * __expf(m - M) + so * __expf(mo - M);
        m = M;
    }
    float inv = 1.f / (s + GAT_EPS);

    // pass 2: weighted bf16 gather
    float4 acc = make_float4(0.f, 0.f, 0.f, 0.f);
    int hh = lane >> 3;   // head owning this lane's 4 output floats
    for (int j0 = 0; j0 < deg; j0 += 8) {
        int idx = j0 + (lane >> 3);
        float p = 0.f;
        if (idx < deg) {
            float l = elogit[(size_t)(rs + j0) * 8 + lane];
            p = __expf(l - m) * inv;
        }
        int sv = 0;
        if (lane < 8 && j0 + lane < deg) sv = csr_src[rs + j0 + lane];
        int cnt = min(8, deg - j0);
        for (int j = 0; j < cnt; ++j) {
            int srcj = __shfl(sv, j);
            float a  = __shfl(p, (j << 3) | hh);
            ushort4 hv = *(const ushort4*)&h1b[(size_t)srcj * 256 + lane * 4];
            acc.x += a * bf2f(hv.x); acc.y += a * bf2f(hv.y);
            acc.z += a * bf2f(hv.z); acc.w += a * bf2f(hv.w);
        }
    }

    // epilogue: +bias1, ELU, dot W2, wave-reduce
    float4 b = *(const float4*)&bias1[lane * 4];
    acc.x += b.x; acc.y += b.y; acc.z += b.z; acc.w += b.w;
    acc.x = acc.x > 0.f ? acc.x : __expf(acc.x) - 1.f;
    acc.y = acc.y > 0.f ? acc.y : __expf(acc.y) - 1.f;
    acc.z = acc.z > 0.f ? acc.z : __expf(acc.z) - 1.f;
    acc.w = acc.w > 0.f ? acc.w : __expf(acc.w) - 1.f;
    float4 w = *(const float4*)&W2[lane * 4];
    float part = acc.x * w.x + acc.y * w.y + acc.z * w.z + acc.w * w.w;
    #pragma unroll
    for (int mask = 1; mask < 64; mask <<= 1) part += __shfl_xor(part, mask);
    if (lane == 0) h2[n] = part;
}

// ---------- fused layer-2: softmax + aggregate + bias + sigmoid (wave per node) ----------
__global__ __launch_bounds__(256) void layer2_fused(
    const int* __restrict__ row_ptr, const int* __restrict__ csr_src,
    const float* __restrict__ h2, const float* __restrict__ a_s2,
    const float* __restrict__ a_d2, const float* __restrict__ bias2,
    float* __restrict__ out, int N)
{
    int n = blockIdx.x * 4 + (threadIdx.x >> 6);
    int lane = threadIdx.x & 63;
    if (n >= N) return;
    int rs = row_ptr[n];
    int deg = row_ptr[n + 1] - rs;
    float asc = a_s2[0], adc = a_d2[0];
    float hdc = h2[n] * adc;

    float m = NEG_BIG, s = 0.f;
    for (int k = lane; k < deg; k += 64) {
        float hs = h2[csr_src[rs + k]];
        float l = leaky(hs * asc + hdc);
        if (l > m) { s = s * __expf(m - l) + 1.f; m = l; }
        else       { s += __expf(l - m); }
    }
    #pragma unroll
    for (int mask = 1; mask < 64; mask <<= 1) {
        float mo = __shfl_xor(m, mask);
        float so = __shfl_xor(s, mask);
        float M = fmaxf(m, mo);
        s = s * __expf(m - M) + so * __expf(mo - M);
        m = M;
    }
    float inv = 1.f / (s + GAT_EPS);

    float acc = 0.f;
    for (int k = lane; k < deg; k += 64) {
        float hs = h2[csr_src[rs + k]];
        float l = leaky(hs * asc + hdc);
        acc += __expf(l - m) * inv * hs;
    }
    #pragma unroll
    for (int mask = 1; mask < 64; mask <<= 1) acc += __shfl_xor(acc, mask);
    if (lane == 0) {
        float z = acc + bias2[0];
        out[n] = 1.f / (1.f + __expf(-z));
    }
}

extern "C" void kernel_launch(void* const* d_in, const int* in_sizes, int n_in,
                              void* d_out, int out_size, void* d_ws, size_t ws_size,
                              hipStream_t stream)
{
    const float* x      = (const float*)d_in[0];
    const int*   ei     = (const int*)  d_in[1];
    const float* W1     = (const float*)d_in[2];
    const float* a_src1 = (const float*)d_in[3];
    const float* a_dst1 = (const float*)d_in[4];
    const float* bias1  = (const float*)d_in[5];
    const float* W2     = (const float*)d_in[6];
    const float* a_s2   = (const float*)d_in[7];
    const float* a_d2   = (const float*)d_in[8];
    const float* bias2  = (const float*)d_in[9];
    float* out = (float*)d_out;

    const int N  = in_sizes[0] / 128;
    const int E  = in_sizes[1] / 2;
    const int ET = E + N;
    const int NB = (N + 1023) / 1024;   // scan blocks (<=64 for N<=65536)

    float* ws = (float*)d_ws;
    size_t off = 0;
    unsigned short* xb  = (unsigned short*)(ws + off);  off += (size_t)N * 64;
    unsigned short* w1t = (unsigned short*)(ws + off);  off += 16384;
    unsigned short* h1b = (unsigned short*)(ws + off);  off += (size_t)N * 128;
    float* as1 = ws + off;                 off += (size_t)N * 8;
    float* ad1 = ws + off;                 off += (size_t)N * 8;
    float* h2  = ws + off;                 off += (size_t)N;
    int* deg     = (int*)(ws + off);       off += (size_t)N;
    int* cursor  = (int*)(ws + off);       off += (size_t)N;
    int* row_ptr = (int*)(ws + off);       off += (size_t)N + 4;
    int* incl    = (int*)(ws + off);       off += (size_t)N;
    int* bsum    = (int*)(ws + off);       off += 64;
    int* boff    = (int*)(ws + off);       off += 64;
    int* csr_src = (int*)(ws + off);       off += (size_t)ET + 16;
    float* elogit = ws + off;              off += (size_t)ET * 8 + 64;

    // prep: bf16 conversions + deg init
    prep_kernel<<<(N * 32 + 255) / 256, 256, 0, stream>>>(x, W1, xb, w1t, deg, N);

    // CSR build
    count_deg<<<(E + 255) / 256, 256, 0, stream>>>(ei, E, deg);
    scan_a<<<NB, 256, 0, stream>>>(deg, incl, bsum, N);
    scan_b<<<1, 64, 0, stream>>>(bsum, boff, NB);
    scan_c<<<NB, 256, 0, stream>>>(incl, boff, deg, row_ptr, cursor, N);

    // layer-1 projection (bf16 MFMA) + logits
    gemm1_mfma<<<(N + 63) / 64, 256, 0, stream>>>(xb, w1t, h1b, N);
    alpha1_kernel<<<(N * 8 + 255) / 256, 256, 0, stream>>>(h1b, a_src1, a_dst1, as1, ad1, N);

    scatter_logits<<<(ET + 255) / 256, 256, 0, stream>>>(ei, E, ET, as1, ad1,
                                                         cursor, csr_src, elogit);

    // fused aggregation layers
    aggr1_fused<<<(N + 3) / 4, 256, 0, stream>>>(row_ptr, csr_src, elogit, h1b,
                                                 bias1, W2, h2, N);
    layer2_fused<<<(N + 3) / 4, 256, 0, stream>>>(row_ptr, csr_src, h2,
                                                  a_s2, a_d2, bias2, out, N);
}

// Round 4
// 290.869 us; speedup vs baseline: 12.8696x; 1.0964x over previous
//
#include <hip/hip_runtime.h>
#include <math.h>

#define NEG_SLOPE 0.2f
#define GAT_EPS 1e-16f
#define NEG_BIG -3.0e38f

typedef __attribute__((ext_vector_type(8))) short short8;
typedef __attribute__((ext_vector_type(4))) float floatx4;

__device__ __forceinline__ float leaky(float v) {
    return v > 0.f ? v : NEG_SLOPE * v;
}
// fp32 -> bf16 round-to-nearest-even
__device__ __forceinline__ unsigned short f2bf(float f) {
    unsigned u = __float_as_uint(f);
    unsigned r = u + 0x7FFFu + ((u >> 16) & 1u);
    return (unsigned short)(r >> 16);
}
__device__ __forceinline__ float bf2f(unsigned short h) {
    return __uint_as_float(((unsigned)h) << 16);
}

// ---------- prep: x -> bf16, W1 -> bf16 transposed [256][128], deg init ----------
__global__ void prep_kernel(const float* __restrict__ x, const float* __restrict__ W1,
    unsigned short* __restrict__ xb, unsigned short* __restrict__ w1t,
    int* __restrict__ deg, int N)
{
    int idx = blockIdx.x * blockDim.x + threadIdx.x;
    int nx4 = N * 32;                       // N*128/4 float4 groups
    if (idx < nx4) {
        float4 v = *(const float4*)&x[(size_t)idx * 4];
        ushort4 o;
        o.x = f2bf(v.x); o.y = f2bf(v.y); o.z = f2bf(v.z); o.w = f2bf(v.w);
        *(ushort4*)&xb[(size_t)idx * 4] = o;
    }
    if (idx < 128 * 256) {                  // w1t[n][k] = W1[k][n]
        int n = idx >> 7, k = idx & 127;
        w1t[idx] = f2bf(W1[(size_t)k * 256 + n]);
    }
    if (idx < N) deg[idx] = 1;              // self-loop
}

// ---------- GEMM1 via bf16 MFMA: h1b[N,256](bf16) = xb[N,128] @ W1 ----------
__global__ __launch_bounds__(256) void gemm1_mfma(
    const unsigned short* __restrict__ xb, const unsigned short* __restrict__ w1t,
    unsigned short* __restrict__ h1b, int N)
{
    __shared__ __align__(16) unsigned short Asl[64][40];
    __shared__ __align__(16) unsigned short Bsl[256][40];
    const int row0 = blockIdx.x * 64;
    const int tid = threadIdx.x;
    const int wave = tid >> 6, lane = tid & 63;
    const int l15 = lane & 15, quad = lane >> 4;

    floatx4 acc[16];
    #pragma unroll
    for (int i = 0; i < 16; ++i) acc[i] = (floatx4){0.f, 0.f, 0.f, 0.f};

    for (int kc = 0; kc < 128; kc += 32) {
        {
            int r = tid >> 2, q = tid & 3;
            int row = row0 + r; if (row > N - 1) row = N - 1;
            uint4 v = *(const uint4*)&xb[(size_t)row * 128 + kc + q * 8];
            *(uint4*)&Asl[r][q * 8] = v;
        }
        {
            int n = tid;
            #pragma unroll
            for (int q = 0; q < 4; ++q) {
                uint4 v = *(const uint4*)&w1t[(size_t)n * 128 + kc + q * 8];
                *(uint4*)&Bsl[n][q * 8] = v;
            }
        }
        __syncthreads();
        short8 a = *(const short8*)&Asl[wave * 16 + l15][quad * 8];
        #pragma unroll
        for (int nt = 0; nt < 16; ++nt) {
            short8 b = *(const short8*)&Bsl[nt * 16 + l15][quad * 8];
            acc[nt] = __builtin_amdgcn_mfma_f32_16x16x32_bf16(a, b, acc[nt], 0, 0, 0);
        }
        __syncthreads();
    }
    #pragma unroll
    for (int reg = 0; reg < 4; ++reg) {
        int row = row0 + wave * 16 + quad * 4 + reg;
        if (row < N) {
            #pragma unroll
            for (int nt = 0; nt < 16; ++nt)
                h1b[(size_t)row * 256 + nt * 16 + l15] = f2bf(acc[nt][reg]);
        }
    }
}

// ---------- per-node attention logits from bf16 h ----------
__global__ void alpha1_kernel(const unsigned short* __restrict__ h1b,
    const float* __restrict__ a_src, const float* __restrict__ a_dst,
    float* __restrict__ as1, float* __restrict__ ad1, int N)
{
    int t = blockIdx.x * blockDim.x + threadIdx.x;
    if (t >= N * 8) return;
    int n = t >> 3, hh = t & 7;
    const unsigned short* hp = h1b + (size_t)n * 256 + hh * 32;
    const float4* asp = (const float4*)(a_src + hh * 32);
    const float4* adp = (const float4*)(a_dst + hh * 32);
    float ss = 0.f, sd = 0.f;
    #pragma unroll
    for (int j = 0; j < 8; ++j) {
        ushort4 hv4 = *(const ushort4*)&hp[j * 4];
        float4 av = asp[j], dv = adp[j];
        float h0 = bf2f(hv4.x), h1 = bf2f(hv4.y), h2 = bf2f(hv4.z), h3 = bf2f(hv4.w);
        ss += h0 * av.x + h1 * av.y + h2 * av.z + h3 * av.w;
        sd += h0 * dv.x + h1 * dv.y + h2 * dv.z + h3 * dv.w;
    }
    as1[t] = ss; ad1[t] = sd;
}

// ---------- CSR build ----------
__global__ void count_deg(const int* __restrict__ ei, int E, int* __restrict__ deg) {
    int i = blockIdx.x * blockDim.x + threadIdx.x;
    if (i < E) atomicAdd(&deg[ei[E + i]], 1);
}

__global__ __launch_bounds__(256) void scan_a(const int* __restrict__ deg,
    int* __restrict__ incl, int* __restrict__ bsum, int N)
{
    __shared__ int wsum[4];
    int t = threadIdx.x, b = blockIdx.x;
    int lane = t & 63, wv = t >> 6;
    int i0 = b * 1024 + t * 4;
    int v0 = (i0 + 0 < N) ? deg[i0 + 0] : 0;
    int v1 = (i0 + 1 < N) ? deg[i0 + 1] : 0;
    int v2 = (i0 + 2 < N) ? deg[i0 + 2] : 0;
    int v3 = (i0 + 3 < N) ? deg[i0 + 3] : 0;
    int tsum = v0 + v1 + v2 + v3;
    int x = tsum;
    #pragma unroll
    for (int off = 1; off < 64; off <<= 1) {
        int y = __shfl_up(x, off);
        if (lane >= off) x += y;
    }
    if (lane == 63) wsum[wv] = x;
    __syncthreads();
    int woff = 0;
    #pragma unroll
    for (int w = 0; w < 4; ++w) if (w < wv) woff += wsum[w];
    int run = woff + x - tsum;
    run += v0; if (i0 + 0 < N) incl[i0 + 0] = run;
    run += v1; if (i0 + 1 < N) incl[i0 + 1] = run;
    run += v2; if (i0 + 2 < N) incl[i0 + 2] = run;
    run += v3; if (i0 + 3 < N) incl[i0 + 3] = run;
    __syncthreads();
    if (t == 255) bsum[b] = woff + x;
}

__global__ void scan_b(int* __restrict__ bsum, int* __restrict__ boff, int nb) {
    int t = threadIdx.x;
    int v = (t < nb) ? bsum[t] : 0;
    int x = v;
    #pragma unroll
    for (int off = 1; off < 64; off <<= 1) {
        int y = __shfl_up(x, off);
        if (t >= off) x += y;
    }
    if (t < nb) boff[t] = x - v;
}

__global__ __launch_bounds__(256) void scan_c(const int* __restrict__ incl,
    const int* __restrict__ boff, const int* __restrict__ deg,
    int* __restrict__ row_ptr, int* __restrict__ cursor, int N)
{
    int t = threadIdx.x, b = blockIdx.x;
    int base = boff[b];
    int i0 = b * 1024 + t * 4;
    #pragma unroll
    for (int j = 0; j < 4; ++j) {
        int i = i0 + j;
        if (i < N) {
            int ip = base + incl[i];
            row_ptr[i + 1] = ip;
            cursor[i] = ip - deg[i];
        }
    }
    if (b == 0 && t == 0) row_ptr[0] = 0;
}

// scatter edges into CSR order + per-edge post-leaky logits (8 heads)
__global__ void scatter_logits(const int* __restrict__ ei, int E, int ET,
    const float* __restrict__ as1, const float* __restrict__ ad1,
    int* __restrict__ cursor, int* __restrict__ csr_src, float* __restrict__ elogit)
{
    int i = blockIdx.x * blockDim.x + threadIdx.x;
    if (i >= ET) return;
    int src = (i < E) ? ei[i] : (i - E);
    int dst = (i < E) ? ei[E + i] : (i - E);
    int pos = atomicAdd(&cursor[dst], 1);
    csr_src[pos] = src;
    const float4* sp = (const float4*)(as1 + (size_t)src * 8);
    const float4* dp = (const float4*)(ad1 + (size_t)dst * 8);
    float4 s0 = sp[0], s1 = sp[1], d0 = dp[0], d1 = dp[1];
    float4 e0 = make_float4(leaky(s0.x + d0.x), leaky(s0.y + d0.y),
                            leaky(s0.z + d0.z), leaky(s0.w + d0.w));
    float4 e1 = make_float4(leaky(s1.x + d1.x), leaky(s1.y + d1.y),
                            leaky(s1.z + d1.z), leaky(s1.w + d1.w));
    *(float4*)&elogit[(size_t)pos * 8]     = e0;
    *(float4*)&elogit[(size_t)pos * 8 + 4] = e1;
}

// ---------- fused layer-1 aggregation + bias + ELU + GEMM2 (wave per node) ----------
__global__ __launch_bounds__(256) void aggr1_fused(
    const int* __restrict__ row_ptr, const int* __restrict__ csr_src,
    const float* __restrict__ elogit, const unsigned short* __restrict__ h1b,
    const float* __restrict__ bias1, const float* __restrict__ W2,
    float* __restrict__ h2, int N)
{
    int n = blockIdx.x * 4 + (threadIdx.x >> 6);
    int lane = threadIdx.x & 63;
    if (n >= N) return;
    int rs = row_ptr[n];
    int deg = row_ptr[n + 1] - rs;

    // pass 1: online softmax; lane -> (edge j0 + (lane>>3), head lane&7)
    float m = NEG_BIG, s = 0.f;
    for (int j0 = 0; j0 < deg; j0 += 8) {
        int idx = j0 + (lane >> 3);
        if (idx < deg) {
            float l = elogit[(size_t)(rs + j0) * 8 + lane];
            if (l > m) { s = s * __expf(m - l) + 1.f; m = l; }
            else       { s += __expf(l - m); }
        }
    }
    #pragma unroll
    for (int mask = 8; mask < 64; mask <<= 1) {
        float mo = __shfl_xor(m, mask);
        float so = __shfl_xor(s, mask);
        float M = fmaxf(m, mo);
        s = s * __expf(m - M) + so * __expf(mo - M);
        m = M;
    }
    float inv = 1.f / (s + GAT_EPS);

    // pass 2: weighted bf16 gather — fixed-8 unrolled so 8 gathers stay in flight.
    // invalid slots: src clamped to 0 (safe row), alpha forced to 0.
    float4 acc = make_float4(0.f, 0.f, 0.f, 0.f);
    int hh = lane >> 3;
    for (int j0 = 0; j0 < deg; j0 += 8) {
        int idx = j0 + (lane >> 3);
        float p = 0.f;
        if (idx < deg) {
            float l = elogit[(size_t)(rs + j0) * 8 + lane];
            p = __expf(l - m) * inv;
        }
        int sv = 0;
        if (lane < 8 && j0 + lane < deg) sv = csr_src[rs + j0 + lane];
        int srcs[8];
        #pragma unroll
        for (int j = 0; j < 8; ++j) srcs[j] = __shfl(sv, j);
        ushort4 hv[8];
        #pragma unroll
        for (int j = 0; j < 8; ++j)
            hv[j] = *(const ushort4*)&h1b[(size_t)srcs[j] * 256 + lane * 4];
        #pragma unroll
        for (int j = 0; j < 8; ++j) {
            float a = __shfl(p, (j << 3) | hh);
            acc.x += a * bf2f(hv[j].x); acc.y += a * bf2f(hv[j].y);
            acc.z += a * bf2f(hv[j].z); acc.w += a * bf2f(hv[j].w);
        }
    }

    // epilogue: +bias1, ELU, dot W2, wave-reduce
    float4 b = *(const float4*)&bias1[lane * 4];
    acc.x += b.x; acc.y += b.y; acc.z += b.z; acc.w += b.w;
    acc.x = acc.x > 0.f ? acc.x : __expf(acc.x) - 1.f;
    acc.y = acc.y > 0.f ? acc.y : __expf(acc.y) - 1.f;
    acc.z = acc.z > 0.f ? acc.z : __expf(acc.z) - 1.f;
    acc.w = acc.w > 0.f ? acc.w : __expf(acc.w) - 1.f;
    float4 w = *(const float4*)&W2[lane * 4];
    float part = acc.x * w.x + acc.y * w.y + acc.z * w.z + acc.w * w.w;
    #pragma unroll
    for (int mask = 1; mask < 64; mask <<= 1) part += __shfl_xor(part, mask);
    if (lane == 0) h2[n] = part;
}

// ---------- fused layer-2: 16 lanes per node (4 nodes/wave) ----------
__global__ __launch_bounds__(256) void layer2_fused(
    const int* __restrict__ row_ptr, const int* __restrict__ csr_src,
    const float* __restrict__ h2, const float* __restrict__ a_s2,
    const float* __restrict__ a_d2, const float* __restrict__ bias2,
    float* __restrict__ out, int N)
{
    int n = blockIdx.x * 16 + (threadIdx.x >> 4);
    int sl = threadIdx.x & 15;
    if (n >= N) return;
    int rs = row_ptr[n];
    int deg = row_ptr[n + 1] - rs;
    float asc = a_s2[0], adc = a_d2[0];
    float hdc = h2[n] * adc;

    // cache first 32 edges (2 per lane) in registers; tail loop for rare deg>32
    int k0 = sl, k1 = sl + 16;
    float hs0 = 0.f, hs1 = 0.f;
    bool v0 = k0 < deg, v1 = k1 < deg;
    if (v0) hs0 = h2[csr_src[rs + k0]];
    if (v1) hs1 = h2[csr_src[rs + k1]];

    float m = NEG_BIG, s = 0.f;
    if (v0) { m = leaky(hs0 * asc + hdc); s = 1.f; }
    if (v1) {
        float l = leaky(hs1 * asc + hdc);
        if (l > m) { s = s * __expf(m - l) + 1.f; m = l; }
        else       { s += __expf(l - m); }
    }
    for (int k = sl + 32; k < deg; k += 16) {
        float hs = h2[csr_src[rs + k]];
        float l = leaky(hs * asc + hdc);
        if (l > m) { s = s * __expf(m - l) + 1.f; m = l; }
        else       { s += __expf(l - m); }
    }
    #pragma unroll
    for (int mask = 1; mask < 16; mask <<= 1) {
        float mo = __shfl_xor(m, mask);
        float so = __shfl_xor(s, mask);
        float M = fmaxf(m, mo);
        s = s * __expf(m - M) + so * __expf(mo - M);
        m = M;
    }
    float inv = 1.f / (s + GAT_EPS);

    float acc = 0.f;
    if (v0) acc += __expf(leaky(hs0 * asc + hdc) - m) * hs0;
    if (v1) acc += __expf(leaky(hs1 * asc + hdc) - m) * hs1;
    for (int k = sl + 32; k < deg; k += 16) {
        float hs = h2[csr_src[rs + k]];
        float l = leaky(hs * asc + hdc);
        acc += __expf(l - m) * hs;
    }
    #pragma unroll
    for (int mask = 1; mask < 16; mask <<= 1) acc += __shfl_xor(acc, mask);
    if (sl == 0) {
        float z = acc * inv + bias2[0];
        out[n] = 1.f / (1.f + __expf(-z));
    }
}

extern "C" void kernel_launch(void* const* d_in, const int* in_sizes, int n_in,
                              void* d_out, int out_size, void* d_ws, size_t ws_size,
                              hipStream_t stream)
{
    const float* x      = (const float*)d_in[0];
    const int*   ei     = (const int*)  d_in[1];
    const float* W1     = (const float*)d_in[2];
    const float* a_src1 = (const float*)d_in[3];
    const float* a_dst1 = (const float*)d_in[4];
    const float* bias1  = (const float*)d_in[5];
    const float* W2     = (const float*)d_in[6];
    const float* a_s2   = (const float*)d_in[7];
    const float* a_d2   = (const float*)d_in[8];
    const float* bias2  = (const float*)d_in[9];
    float* out = (float*)d_out;

    const int N  = in_sizes[0] / 128;
    const int E  = in_sizes[1] / 2;
    const int ET = E + N;
    const int NB = (N + 1023) / 1024;

    float* ws = (float*)d_ws;
    size_t off = 0;
    unsigned short* xb  = (unsigned short*)(ws + off);  off += (size_t)N * 64;
    unsigned short* w1t = (unsigned short*)(ws + off);  off += 16384;
    unsigned short* h1b = (unsigned short*)(ws + off);  off += (size_t)N * 128;
    float* as1 = ws + off;                 off += (size_t)N * 8;
    float* ad1 = ws + off;                 off += (size_t)N * 8;
    float* h2  = ws + off;                 off += (size_t)N;
    int* deg     = (int*)(ws + off);       off += (size_t)N;
    int* cursor  = (int*)(ws + off);       off += (size_t)N;
    int* row_ptr = (int*)(ws + off);       off += (size_t)N + 4;
    int* incl    = (int*)(ws + off);       off += (size_t)N;
    int* bsum    = (int*)(ws + off);       off += 64;
    int* boff    = (int*)(ws + off);       off += 64;
    int* csr_src = (int*)(ws + off);       off += (size_t)ET + 16;
    float* elogit = ws + off;              off += (size_t)ET * 8 + 64;

    prep_kernel<<<(N * 32 + 255) / 256, 256, 0, stream>>>(x, W1, xb, w1t, deg, N);

    count_deg<<<(E + 255) / 256, 256, 0, stream>>>(ei, E, deg);
    scan_a<<<NB, 256, 0, stream>>>(deg, incl, bsum, N);
    scan_b<<<1, 64, 0, stream>>>(bsum, boff, NB);
    scan_c<<<NB, 256, 0, stream>>>(incl, boff, deg, row_ptr, cursor, N);

    gemm1_mfma<<<(N + 63) / 64, 256, 0, stream>>>(xb, w1t, h1b, N);
    alpha1_kernel<<<(N * 8 + 255) / 256, 256, 0, stream>>>(h1b, a_src1, a_dst1, as1, ad1, N);

    scatter_logits<<<(ET + 255) / 256, 256, 0, stream>>>(ei, E, ET, as1, ad1,
                                                         cursor, csr_src, elogit);

    aggr1_fused<<<(N + 3) / 4, 256, 0, stream>>>(row_ptr, csr_src, elogit, h1b,
                                                 bias1, W2, h2, N);
    layer2_fused<<<(N + 15) / 16, 256, 0, stream>>>(row_ptr, csr_src, h2,
                                                    a_s2, a_d2, bias2, out, N);
}

// Round 5
// 271.638 us; speedup vs baseline: 13.7807x; 1.0708x over previous
//
#include <hip/hip_runtime.h>
#include <math.h>

#define NEG_SLOPE 0.2f
#define GAT_EPS 1e-16f
#define NEG_BIG -3.0e38f

typedef __attribute__((ext_vector_type(8))) short short8;
typedef __attribute__((ext_vector_type(4))) float floatx4;

__device__ __forceinline__ float leaky(float v) {
    return v > 0.f ? v : NEG_SLOPE * v;
}
// fp32 -> bf16 round-to-nearest-even
__device__ __forceinline__ unsigned short f2bf(float f) {
    unsigned u = __float_as_uint(f);
    unsigned r = u + 0x7FFFu + ((u >> 16) & 1u);
    return (unsigned short)(r >> 16);
}
__device__ __forceinline__ float bf2f(unsigned short h) {
    return __uint_as_float(((unsigned)h) << 16);
}

// ---------- prep: x->bf16, W1->bf16 transposed [272][128] (includes W1@P cols),
//            fused in-degree count (deg pre-zeroed by memset) ----------
__global__ void prep_kernel(const float* __restrict__ x, const float* __restrict__ W1,
    const float* __restrict__ a_src, const float* __restrict__ a_dst,
    const int* __restrict__ ei,
    unsigned short* __restrict__ xb, unsigned short* __restrict__ w1t,
    int* __restrict__ deg, int N, int E)
{
    int idx = blockIdx.x * blockDim.x + threadIdx.x;
    int nx4 = N * 32;                       // N*128/4 float4 groups
    if (idx < nx4) {
        float4 v = *(const float4*)&x[(size_t)idx * 4];
        ushort4 o;
        o.x = f2bf(v.x); o.y = f2bf(v.y); o.z = f2bf(v.z); o.w = f2bf(v.w);
        *(ushort4*)&xb[(size_t)idx * 4] = o;
    }
    if (idx < 128 * 256) {                  // w1t[n][k] = W1[k][n], n in [0,256)
        int n = idx >> 7, k = idx & 127;
        w1t[idx] = f2bf(W1[(size_t)k * 256 + n]);
    }
    if (idx < 2048) {                       // W1P: cols 256..271: as/ad projections
        int j = idx >> 7, k = idx & 127;    // j 0..15 (0-7 src, 8-15 dst)
        const float* a = (j < 8) ? (a_src + j * 32) : (a_dst + (j - 8) * 32);
        const float* wr = W1 + (size_t)k * 256 + (j & 7) * 32;
        float s = 0.f;
        #pragma unroll
        for (int c = 0; c < 32; ++c) s += wr[c] * a[c];
        w1t[(size_t)(256 + j) * 128 + k] = f2bf(s);
    }
    if (idx < E) atomicAdd(&deg[ei[E + idx]], 1);
}

// ---------- GEMM1 via bf16 MFMA: h1b[N,256](bf16) + as1/ad1[N,8] fused ----------
__global__ __launch_bounds__(256) void gemm1_mfma(
    const unsigned short* __restrict__ xb, const unsigned short* __restrict__ w1t,
    unsigned short* __restrict__ h1b, float* __restrict__ as1, float* __restrict__ ad1,
    int N)
{
    __shared__ __align__(16) unsigned short Asl[64][40];
    __shared__ __align__(16) unsigned short Bsl[272][40];
    const int row0 = blockIdx.x * 64;
    const int tid = threadIdx.x;
    const int wave = tid >> 6, lane = tid & 63;
    const int l15 = lane & 15, quad = lane >> 4;

    floatx4 acc[17];
    #pragma unroll
    for (int i = 0; i < 17; ++i) acc[i] = (floatx4){0.f, 0.f, 0.f, 0.f};

    for (int kc = 0; kc < 128; kc += 32) {
        {   // stage A: 64 rows x 32 k
            int r = tid >> 2, q = tid & 3;
            int row = row0 + r; if (row > N - 1) row = N - 1;
            uint4 v = *(const uint4*)&xb[(size_t)row * 128 + kc + q * 8];
            *(uint4*)&Asl[r][q * 8] = v;
        }
        {   // stage B: 272 n x 32 k
            #pragma unroll
            for (int q = 0; q < 4; ++q) {
                uint4 v = *(const uint4*)&w1t[(size_t)tid * 128 + kc + q * 8];
                *(uint4*)&Bsl[tid][q * 8] = v;
            }
            if (tid < 16) {
                #pragma unroll
                for (int q = 0; q < 4; ++q) {
                    uint4 v = *(const uint4*)&w1t[(size_t)(256 + tid) * 128 + kc + q * 8];
                    *(uint4*)&Bsl[256 + tid][q * 8] = v;
                }
            }
        }
        __syncthreads();
        short8 a = *(const short8*)&Asl[wave * 16 + l15][quad * 8];
        #pragma unroll
        for (int nt = 0; nt < 17; ++nt) {
            short8 b = *(const short8*)&Bsl[nt * 16 + l15][quad * 8];
            acc[nt] = __builtin_amdgcn_mfma_f32_16x16x32_bf16(a, b, acc[nt], 0, 0, 0);
        }
        __syncthreads();
    }
    // epilogue: D row = quad*4+reg, col = nt*16+l15
    #pragma unroll
    for (int reg = 0; reg < 4; ++reg) {
        int row = row0 + wave * 16 + quad * 4 + reg;
        if (row < N) {
            #pragma unroll
            for (int nt = 0; nt < 16; ++nt)
                h1b[(size_t)row * 256 + nt * 16 + l15] = f2bf(acc[nt][reg]);
            // 17th tile: cols 256..271 -> as1 (l15<8) / ad1 (l15>=8)
            float v = acc[16][reg];
            if (l15 < 8) as1[(size_t)row * 8 + l15] = v;
            else         ad1[(size_t)row * 8 + l15 - 8] = v;
        }
    }
}

// ---------- CSR scan (self-loop +1 folded in) ----------
__global__ __launch_bounds__(256) void scan_a(const int* __restrict__ deg,
    int* __restrict__ incl, int* __restrict__ bsum, int N)
{
    __shared__ int wsum[4];
    int t = threadIdx.x, b = blockIdx.x;
    int lane = t & 63, wv = t >> 6;
    int i0 = b * 1024 + t * 4;
    int v0 = (i0 + 0 < N) ? deg[i0 + 0] + 1 : 0;
    int v1 = (i0 + 1 < N) ? deg[i0 + 1] + 1 : 0;
    int v2 = (i0 + 2 < N) ? deg[i0 + 2] + 1 : 0;
    int v3 = (i0 + 3 < N) ? deg[i0 + 3] + 1 : 0;
    int tsum = v0 + v1 + v2 + v3;
    int x = tsum;
    #pragma unroll
    for (int off = 1; off < 64; off <<= 1) {
        int y = __shfl_up(x, off);
        if (lane >= off) x += y;
    }
    if (lane == 63) wsum[wv] = x;
    __syncthreads();
    int woff = 0;
    #pragma unroll
    for (int w = 0; w < 4; ++w) if (w < wv) woff += wsum[w];
    int run = woff + x - tsum;
    run += v0; if (i0 + 0 < N) incl[i0 + 0] = run;
    run += v1; if (i0 + 1 < N) incl[i0 + 1] = run;
    run += v2; if (i0 + 2 < N) incl[i0 + 2] = run;
    run += v3; if (i0 + 3 < N) incl[i0 + 3] = run;
    __syncthreads();
    if (t == 255) bsum[b] = woff + x;
}

__global__ void scan_b(int* __restrict__ bsum, int* __restrict__ boff, int nb) {
    int t = threadIdx.x;
    int v = (t < nb) ? bsum[t] : 0;
    int x = v;
    #pragma unroll
    for (int off = 1; off < 64; off <<= 1) {
        int y = __shfl_up(x, off);
        if (t >= off) x += y;
    }
    if (t < nb) boff[t] = x - v;
}

__global__ __launch_bounds__(256) void scan_c(const int* __restrict__ incl,
    const int* __restrict__ boff, const int* __restrict__ deg,
    int* __restrict__ row_ptr, int* __restrict__ cursor, int N)
{
    int t = threadIdx.x, b = blockIdx.x;
    int base = boff[b];
    int i0 = b * 1024 + t * 4;
    #pragma unroll
    for (int j = 0; j < 4; ++j) {
        int i = i0 + j;
        if (i < N) {
            int ip = base + incl[i];
            row_ptr[i + 1] = ip;
            cursor[i] = ip - (deg[i] + 1);
        }
    }
    if (b == 0 && t == 0) row_ptr[0] = 0;
}

// ---------- scatter edges into CSR order (src only) ----------
__global__ void scatter_csr(const int* __restrict__ ei, int E, int ET,
    int* __restrict__ cursor, int* __restrict__ csr_src)
{
    int i = blockIdx.x * blockDim.x + threadIdx.x;
    if (i >= ET) return;
    int src = (i < E) ? ei[i] : (i - E);
    int dst = (i < E) ? ei[E + i] : (i - E);
    int pos = atomicAdd(&cursor[dst], 1);
    csr_src[pos] = src;
}

// ---------- fused layer-1: single-pass online softmax + gather + bias + ELU + GEMM2 ----------
// one wave per dst node. Lane roles:
//   logit role:  lane computes logit for (edge chunk slot le=lane>>3, head lh=lane&7)
//   accum role:  lane owns output channels [lane*4, lane*4+4), i.e. head hh=lane>>3
__global__ __launch_bounds__(256) void aggr1_fused(
    const int* __restrict__ row_ptr, const int* __restrict__ csr_src,
    const float* __restrict__ as1, const float* __restrict__ ad1,
    const unsigned short* __restrict__ h1b,
    const float* __restrict__ bias1, const float* __restrict__ W2,
    float* __restrict__ h2, int N)
{
    int n = blockIdx.x * 4 + (threadIdx.x >> 6);
    int lane = threadIdx.x & 63;
    if (n >= N) return;
    int rs = row_ptr[n];
    int deg = row_ptr[n + 1] - rs;
    int le = lane >> 3, lh = lane & 7, hh = lane >> 3;
    float adv = ad1[(size_t)n * 8 + lh];

    float m = NEG_BIG, s = 0.f;
    float4 acc = make_float4(0.f, 0.f, 0.f, 0.f);

    for (int j0 = 0; j0 < deg; j0 += 8) {
        int sv = 0;
        if (lane < 8 && j0 + lane < deg) sv = csr_src[rs + j0 + lane];
        int srcs[8];
        #pragma unroll
        for (int j = 0; j < 8; ++j) srcs[j] = __shfl(sv, j);
        // my logit (edge j0+le, head lh); as1 is L2-resident
        float l = NEG_BIG;
        if (j0 + le < deg) l = leaky(as1[(size_t)srcs[le] * 8 + lh] + adv);
        // gather 8 h-rows (bf16, 8B/lane each) — all independent, stay in flight
        ushort4 hv[8];
        #pragma unroll
        for (int j = 0; j < 8; ++j)
            hv[j] = *(const ushort4*)&h1b[(size_t)srcs[j] * 256 + lane * 4];
        // collect the 8 logits for my accumulation head hh
        float lj[8];
        #pragma unroll
        for (int j = 0; j < 8; ++j) lj[j] = __shfl(l, (j << 3) | hh);
        float Mc = lj[0];
        #pragma unroll
        for (int j = 1; j < 8; ++j) Mc = fmaxf(Mc, lj[j]);
        float mn = fmaxf(m, Mc);
        float sc = __expf(m - mn);     // first chunk: exp(NEG_BIG-finite)=0
        s *= sc;
        acc.x *= sc; acc.y *= sc; acc.z *= sc; acc.w *= sc;
        #pragma unroll
        for (int j = 0; j < 8; ++j) {
            float p = __expf(lj[j] - mn);   // invalid lj=NEG_BIG -> 0
            s += p;
            acc.x += p * bf2f(hv[j].x); acc.y += p * bf2f(hv[j].y);
            acc.z += p * bf2f(hv[j].z); acc.w += p * bf2f(hv[j].w);
        }
        m = mn;
    }
    float inv = 1.f / (s + GAT_EPS);
    acc.x *= inv; acc.y *= inv; acc.z *= inv; acc.w *= inv;

    // epilogue: +bias1, ELU, dot W2, wave-reduce
    float4 b = *(const float4*)&bias1[lane * 4];
    acc.x += b.x; acc.y += b.y; acc.z += b.z; acc.w += b.w;
    acc.x = acc.x > 0.f ? acc.x : __expf(acc.x) - 1.f;
    acc.y = acc.y > 0.f ? acc.y : __expf(acc.y) - 1.f;
    acc.z = acc.z > 0.f ? acc.z : __expf(acc.z) - 1.f;
    acc.w = acc.w > 0.f ? acc.w : __expf(acc.w) - 1.f;
    float4 w = *(const float4*)&W2[lane * 4];
    float part = acc.x * w.x + acc.y * w.y + acc.z * w.z + acc.w * w.w;
    #pragma unroll
    for (int mask = 1; mask < 64; mask <<= 1) part += __shfl_xor(part, mask);
    if (lane == 0) h2[n] = part;
}

// ---------- fused layer-2: 16 lanes per node (4 nodes/wave) ----------
__global__ __launch_bounds__(256) void layer2_fused(
    const int* __restrict__ row_ptr, const int* __restrict__ csr_src,
    const float* __restrict__ h2, const float* __restrict__ a_s2,
    const float* __restrict__ a_d2, const float* __restrict__ bias2,
    float* __restrict__ out, int N)
{
    int n = blockIdx.x * 16 + (threadIdx.x >> 4);
    int sl = threadIdx.x & 15;
    if (n >= N) return;
    int rs = row_ptr[n];
    int deg = row_ptr[n + 1] - rs;
    float asc = a_s2[0], adc = a_d2[0];
    float hdc = h2[n] * adc;

    int k0 = sl, k1 = sl + 16;
    float hs0 = 0.f, hs1 = 0.f;
    bool v0 = k0 < deg, v1 = k1 < deg;
    if (v0) hs0 = h2[csr_src[rs + k0]];
    if (v1) hs1 = h2[csr_src[rs + k1]];

    float m = NEG_BIG, s = 0.f;
    if (v0) { m = leaky(hs0 * asc + hdc); s = 1.f; }
    if (v1) {
        float l = leaky(hs1 * asc + hdc);
        if (l > m) { s = s * __expf(m - l) + 1.f; m = l; }
        else       { s += __expf(l - m); }
    }
    for (int k = sl + 32; k < deg; k += 16) {
        float hs = h2[csr_src[rs + k]];
        float l = leaky(hs * asc + hdc);
        if (l > m) { s = s * __expf(m - l) + 1.f; m = l; }
        else       { s += __expf(l - m); }
    }
    #pragma unroll
    for (int mask = 1; mask < 16; mask <<= 1) {
        float mo = __shfl_xor(m, mask);
        float so = __shfl_xor(s, mask);
        float M = fmaxf(m, mo);
        s = s * __expf(m - M) + so * __expf(mo - M);
        m = M;
    }
    float inv = 1.f / (s + GAT_EPS);

    float acc = 0.f;
    if (v0) acc += __expf(leaky(hs0 * asc + hdc) - m) * hs0;
    if (v1) acc += __expf(leaky(hs1 * asc + hdc) - m) * hs1;
    for (int k = sl + 32; k < deg; k += 16) {
        float hs = h2[csr_src[rs + k]];
        float l = leaky(hs * asc + hdc);
        acc += __expf(l - m) * hs;
    }
    #pragma unroll
    for (int mask = 1; mask < 16; mask <<= 1) acc += __shfl_xor(acc, mask);
    if (sl == 0) {
        float z = acc * inv + bias2[0];
        out[n] = 1.f / (1.f + __expf(-z));
    }
}

extern "C" void kernel_launch(void* const* d_in, const int* in_sizes, int n_in,
                              void* d_out, int out_size, void* d_ws, size_t ws_size,
                              hipStream_t stream)
{
    const float* x      = (const float*)d_in[0];
    const int*   ei     = (const int*)  d_in[1];
    const float* W1     = (const float*)d_in[2];
    const float* a_src1 = (const float*)d_in[3];
    const float* a_dst1 = (const float*)d_in[4];
    const float* bias1  = (const float*)d_in[5];
    const float* W2     = (const float*)d_in[6];
    const float* a_s2   = (const float*)d_in[7];
    const float* a_d2   = (const float*)d_in[8];
    const float* bias2  = (const float*)d_in[9];
    float* out = (float*)d_out;

    const int N  = in_sizes[0] / 128;
    const int E  = in_sizes[1] / 2;
    const int ET = E + N;
    const int NB = (N + 1023) / 1024;

    float* ws = (float*)d_ws;
    size_t off = 0;
    unsigned short* xb  = (unsigned short*)(ws + off);  off += (size_t)N * 64;
    unsigned short* w1t = (unsigned short*)(ws + off);  off += 17408;  // 272*128 bf16
    unsigned short* h1b = (unsigned short*)(ws + off);  off += (size_t)N * 128;
    float* as1 = ws + off;                 off += (size_t)N * 8;
    float* ad1 = ws + off;                 off += (size_t)N * 8;
    float* h2  = ws + off;                 off += (size_t)N;
    int* deg     = (int*)(ws + off);       off += (size_t)N;
    int* cursor  = (int*)(ws + off);       off += (size_t)N;
    int* row_ptr = (int*)(ws + off);       off += (size_t)N + 4;
    int* incl    = (int*)(ws + off);       off += (size_t)N;
    int* bsum    = (int*)(ws + off);       off += 64;
    int* boff    = (int*)(ws + off);       off += 64;
    int* csr_src = (int*)(ws + off);       off += (size_t)ET + 16;

    hipMemsetAsync(deg, 0, (size_t)N * sizeof(int), stream);

    int prep_n = N * 32; if (prep_n < E) prep_n = E;
    prep_kernel<<<(prep_n + 255) / 256, 256, 0, stream>>>(x, W1, a_src1, a_dst1, ei,
                                                          xb, w1t, deg, N, E);

    scan_a<<<NB, 256, 0, stream>>>(deg, incl, bsum, N);
    scan_b<<<1, 64, 0, stream>>>(bsum, boff, NB);
    scan_c<<<NB, 256, 0, stream>>>(incl, boff, deg, row_ptr, cursor, N);

    scatter_csr<<<(ET + 255) / 256, 256, 0, stream>>>(ei, E, ET, cursor, csr_src);

    gemm1_mfma<<<(N + 63) / 64, 256, 0, stream>>>(xb, w1t, h1b, as1, ad1, N);

    aggr1_fused<<<(N + 3) / 4, 256, 0, stream>>>(row_ptr, csr_src, as1, ad1, h1b,
                                                 bias1, W2, h2, N);
    layer2_fused<<<(N + 15) / 16, 256, 0, stream>>>(row_ptr, csr_src, h2,
                                                    a_s2, a_d2, bias2, out, N);
}